// Round 2
// baseline (624.053 us; speedup 1.0000x reference)
//
#include <hip/hip_runtime.h>
#include <hip/hip_bf16.h>

#define NPG 258
#define DEG 8
#define EPG (NPG * DEG)   // 2064
#define CH 32
#define FIN 64
#define NB 1024           // graphs
#define NTOT (NB * NPG)   // 264192
#define HID 128
#define KSPL 8

// ---------------------------------------------------------------------------
// K1: fused ChebConv. One block per graph.
//   Phase A: y1[n][c] = x[n] . W1[:,c]          (written to hy, global)
//   Phase B: acc[dst][c] += w_e * y1[src][c]    (LDS atomics, graph-local)
//   Phase C: hy[n][c] = elu(x[n].W0[:,c] + b[c] + acc[n][c])  (overwrites y1)
// ---------------------------------------------------------------------------
__global__ __launch_bounds__(256) void conv_fused(
    const float* __restrict__ x, const int* __restrict__ esrc,
    const int* __restrict__ edst, const float* __restrict__ ew,
    const float* __restrict__ W0, const float* __restrict__ W1,
    const float* __restrict__ bc, float* __restrict__ hy)
{
    __shared__ float acc[NPG * CH];            // 33024 B
    const int g   = blockIdx.x;
    const int tid = threadIdx.x;
    const int n0  = g * NPG;
    const int c   = tid & 31;                  // fixed output channel per thread

    // hoist W1 column into registers
    float wc[FIN];
#pragma unroll
    for (int f = 0; f < FIN; ++f) wc[f] = W1[f * CH + c];

    // Phase A + zero acc
    for (int it = tid; it < NPG * CH; it += 256) {
        const int n = it >> 5;
        const float4* xr = reinterpret_cast<const float4*>(x + (size_t)(n0 + n) * FIN);
        float s = 0.f;
#pragma unroll
        for (int f4 = 0; f4 < 16; ++f4) {
            const float4 v = xr[f4];
            s += v.x * wc[f4 * 4 + 0] + v.y * wc[f4 * 4 + 1]
               + v.z * wc[f4 * 4 + 2] + v.w * wc[f4 * 4 + 3];
        }
        hy[(size_t)(n0 + n) * CH + c] = s;
        acc[it] = 0.f;
    }
    __syncthreads();

    // Phase B: scatter-add over this graph's 2064 edges, 8 float4s each
    const int eb = g * EPG;
    for (int it = tid; it < EPG * 8; it += 256) {
        const int e = it >> 3, q = it & 7;
        const int src = esrc[eb + e];          // global node index (within graph)
        const int dl  = edst[eb + e] - n0;     // local dst
        const float w = ew[eb + e];
        const float4 v = *reinterpret_cast<const float4*>(hy + (size_t)src * CH + q * 4);
        float* a = acc + dl * CH + q * 4;
        atomicAdd(a + 0, w * v.x);
        atomicAdd(a + 1, w * v.y);
        atomicAdd(a + 2, w * v.z);
        atomicAdd(a + 3, w * v.w);
    }
    __syncthreads();

    // Phase C: reuse wc for W0 column
#pragma unroll
    for (int f = 0; f < FIN; ++f) wc[f] = W0[f * CH + c];
    const float bias = bc[c];

    for (int it = tid; it < NPG * CH; it += 256) {
        const int n = it >> 5;
        const float4* xr = reinterpret_cast<const float4*>(x + (size_t)(n0 + n) * FIN);
        float s = bias + acc[it];
#pragma unroll
        for (int f4 = 0; f4 < 16; ++f4) {
            const float4 v = xr[f4];
            s += v.x * wc[f4 * 4 + 0] + v.y * wc[f4 * 4 + 1]
               + v.z * wc[f4 * 4 + 2] + v.w * wc[f4 * 4 + 3];
        }
        hy[(size_t)(n0 + n) * CH + c] = (s > 0.f) ? s : expm1f(s);
    }
}

// ---------------------------------------------------------------------------
// K2: GEMM1 partials.  part[ks][m][c] = sum_{k in chunk ks} h[m][k]*Wd1[k][c]
// BM=16, BN=128, BK=64; grid (64 Mtiles, 8 K-splits)
// ---------------------------------------------------------------------------
__global__ __launch_bounds__(256) void gemm1_part(
    const float* __restrict__ h, const float* __restrict__ Wd1,
    float* __restrict__ part)
{
    __shared__ float As[16][64];     // 4 KB
    __shared__ float Bs[64][128];    // 32 KB
    const int mt  = blockIdx.x;      // 0..63
    const int ks  = blockIdx.y;      // 0..7
    const int tid = threadIdx.x;
    const int s0  = (ks * 129) / KSPL;
    const int s1  = ((ks + 1) * 129) / KSPL;

    const int rg = tid >> 5;         // 0..7  -> rows rg*2, rg*2+1
    const int cg = tid & 31;         // 0..31 -> cols cg*4..cg*4+3
    const int r0 = rg * 2;
    const int c0 = cg * 4;

    float4 acc0 = {0.f, 0.f, 0.f, 0.f};
    float4 acc1 = {0.f, 0.f, 0.f, 0.f};

    const int ar = tid >> 4, af = tid & 15;            // A staging map

    for (int s = s0; s < s1; ++s) {
        const int k0 = s * 64;
        // stage A tile [16][64]: one float4 per thread
        *reinterpret_cast<float4*>(&As[ar][af * 4]) =
            *reinterpret_cast<const float4*>(h + (size_t)(mt * 16 + ar) * 8256 + k0 + af * 4);
        // stage B tile [64][128]: 8 float4 per thread
#pragma unroll
        for (int i = 0; i < 8; ++i) {
            const int idx = tid + i * 256;
            const int kr = idx >> 5, f4 = idx & 31;
            *reinterpret_cast<float4*>(&Bs[kr][f4 * 4]) =
                *reinterpret_cast<const float4*>(Wd1 + (size_t)(k0 + kr) * 128 + f4 * 4);
        }
        __syncthreads();
#pragma unroll 16
        for (int k = 0; k < 64; ++k) {
            const float a0 = As[r0][k];
            const float a1 = As[r0 + 1][k];
            const float4 b = *reinterpret_cast<const float4*>(&Bs[k][c0]);
            acc0.x += a0 * b.x; acc0.y += a0 * b.y; acc0.z += a0 * b.z; acc0.w += a0 * b.w;
            acc1.x += a1 * b.x; acc1.y += a1 * b.y; acc1.z += a1 * b.z; acc1.w += a1 * b.w;
        }
        __syncthreads();
    }

    float* p = part + ((size_t)ks * 1024 + (size_t)mt * 16) * 128;
    *reinterpret_cast<float4*>(p + (size_t)(r0 + 0) * 128 + c0) = acc0;
    *reinterpret_cast<float4*>(p + (size_t)(r0 + 1) * 128 + c0) = acc1;
}

// ---------------------------------------------------------------------------
// K3: MLP tail. 4 rows per block (one wave each).
//   h1 = relu(sum_s part[s] + bd1); h2 = relu(h1@Wd2+bd2);
//   h3 = relu(h2@Wd3+bd3); out = sigmoid(h3@Wd4+bd4)
// ---------------------------------------------------------------------------
__global__ __launch_bounds__(256) void mlp_tail(
    const float* __restrict__ part, const float* __restrict__ bd1,
    const float* __restrict__ Wd2, const float* __restrict__ bd2,
    const float* __restrict__ Wd3, const float* __restrict__ bd3,
    const float* __restrict__ Wd4, const float* __restrict__ bd4,
    float* __restrict__ out)
{
    __shared__ float w2[128 * 64];   // 32 KB
    __shared__ float w3[64 * 32];    // 8 KB
    __shared__ float w4[32];
    __shared__ float h1s[4][128];
    __shared__ float h2s[4][64];
    __shared__ float h3s[4][32];

    const int tid = threadIdx.x;
    for (int i = tid; i < 128 * 64; i += 256) w2[i] = Wd2[i];
    for (int i = tid; i < 64 * 32; i += 256)  w3[i] = Wd3[i];
    if (tid < 32) w4[tid] = Wd4[tid];

    const int r    = tid >> 6;       // local row 0..3
    const int lane = tid & 63;
    const int row  = blockIdx.x * 4 + r;

    // layer1: reduce 8 partials, +bias, relu (2 cols per lane)
    float s0 = bd1[lane], s1 = bd1[lane + 64];
#pragma unroll
    for (int s = 0; s < KSPL; ++s) {
        const float* p = part + ((size_t)s * 1024 + row) * 128;
        s0 += p[lane];
        s1 += p[lane + 64];
    }
    h1s[r][lane]      = fmaxf(s0, 0.f);
    h1s[r][lane + 64] = fmaxf(s1, 0.f);
    __syncthreads();

    // layer2: 128 -> 64
    float s2 = bd2[lane];
#pragma unroll 8
    for (int k = 0; k < 128; ++k) s2 += h1s[r][k] * w2[k * 64 + lane];
    h2s[r][lane] = fmaxf(s2, 0.f);
    __syncthreads();

    // layer3: 64 -> 32 (lanes 0..31)
    if (lane < 32) {
        float s3 = bd3[lane];
#pragma unroll 8
        for (int k = 0; k < 64; ++k) s3 += h2s[r][k] * w3[k * 32 + lane];
        h3s[r][lane] = fmaxf(s3, 0.f);
    }
    __syncthreads();

    // layer4: dot(32) + sigmoid
    float p4 = (lane < 32) ? h3s[r][lane] * w4[lane] : 0.f;
#pragma unroll
    for (int off = 32; off > 0; off >>= 1) p4 += __shfl_down(p4, off, 64);
    if (lane == 0) out[row] = 1.f / (1.f + expf(-(p4 + bd4[0])));
}

// ---------------------------------------------------------------------------
extern "C" void kernel_launch(void* const* d_in, const int* in_sizes, int n_in,
                              void* d_out, int out_size, void* d_ws, size_t ws_size,
                              hipStream_t stream)
{
    const float* x    = (const float*)d_in[0];
    const int*   esrc = (const int*)d_in[1];
    const int*   edst = (const int*)d_in[2];
    const float* ew   = (const float*)d_in[3];
    const float* W0   = (const float*)d_in[4];
    const float* W1   = (const float*)d_in[5];
    const float* bc   = (const float*)d_in[6];
    const float* Wd1  = (const float*)d_in[7];
    const float* bd1  = (const float*)d_in[8];
    const float* Wd2  = (const float*)d_in[9];
    const float* bd2  = (const float*)d_in[10];
    const float* Wd3  = (const float*)d_in[11];
    const float* bd3  = (const float*)d_in[12];
    const float* Wd4  = (const float*)d_in[13];
    const float* bd4  = (const float*)d_in[14];
    float* out = (float*)d_out;

    float* hy   = (float*)d_ws;                          // [NTOT][32], also h
    float* part = hy + (size_t)NTOT * CH;                // [8][1024][128]

    conv_fused<<<NB, 256, 0, stream>>>(x, esrc, edst, ew, W0, W1, bc, hy);
    gemm1_part<<<dim3(64, KSPL), 256, 0, stream>>>(hy, Wd1, part);
    mlp_tail<<<256, 256, 0, stream>>>(part, bd1, Wd2, bd2, Wd3, bd3, Wd4, bd4, out);
}

// Round 3
// 600.664 us; speedup vs baseline: 1.0389x; 1.0389x over previous
//
#include <hip/hip_runtime.h>
#include <hip/hip_bf16.h>

#define NPG 258
#define DEG 8
#define EPG (NPG * DEG)   // 2064
#define CH 32
#define FIN 64
#define NB 1024           // graphs
#define NTOT (NB * NPG)   // 264192
#define HID 128
#define KSPL 8
#define KTOT 8256         // NPG*CH
#define Y1S 40            // y1 LDS stride (bf16 elems): 80B rows, bank-spread
#define ACS 36            // acc LDS stride (f32 elems): 144B rows, bank-spread

typedef __attribute__((ext_vector_type(8))) short bf16x8;
typedef __attribute__((ext_vector_type(4))) float f32x4;

__device__ inline unsigned short f2bf(float f) {
    __hip_bfloat16 b = __float2bfloat16(f);
    return *reinterpret_cast<unsigned short*>(&b);
}
__device__ inline float bfbits2f(unsigned int u) {   // low 16 bits hold a bf16
    unsigned int v = u << 16;
    return __builtin_bit_cast(float, v);
}

// ---------------------------------------------------------------------------
// K1: fused ChebConv, one block per graph. y1 (bf16) and acc (f32) both LDS.
//   A: y1s[n][c] = x[n].W1[:,c]
//   B: acc[dst][c] += w_e * y1s[src][c]   (padded-stride LDS atomics)
//   C: h[n][c] = elu(x[n].W0[:,c] + b[c] + acc[n][c])  -> bf16 global
// ---------------------------------------------------------------------------
__global__ __launch_bounds__(256) void conv_fused(
    const float* __restrict__ x, const int* __restrict__ esrc,
    const int* __restrict__ edst, const float* __restrict__ ew,
    const float* __restrict__ W0, const float* __restrict__ W1,
    const float* __restrict__ bc, __hip_bfloat16* __restrict__ hy)
{
    __shared__ unsigned short y1s[NPG * Y1S];  // 20640 B
    __shared__ float acc[NPG * ACS];           // 37152 B  (total 57792 B)
    const int g   = blockIdx.x;
    const int tid = threadIdx.x;
    const int n0  = g * NPG;
    const int c   = tid & 31;

    float wc[FIN];
#pragma unroll
    for (int f = 0; f < FIN; ++f) wc[f] = W1[f * CH + c];

    // Phase A: y1 -> LDS (bf16)
    for (int it = tid; it < NPG * CH; it += 256) {
        const int n = it >> 5;
        const float4* xr = reinterpret_cast<const float4*>(x + (size_t)(n0 + n) * FIN);
        float s = 0.f;
#pragma unroll
        for (int f4 = 0; f4 < 16; ++f4) {
            const float4 v = xr[f4];
            s += v.x * wc[f4 * 4 + 0] + v.y * wc[f4 * 4 + 1]
               + v.z * wc[f4 * 4 + 2] + v.w * wc[f4 * 4 + 3];
        }
        y1s[n * Y1S + c] = f2bf(s);
    }
    for (int it = tid; it < NPG * ACS; it += 256) acc[it] = 0.f;
    __syncthreads();

    // Phase B: graph-local scatter, 8 lanes per edge (4 channels each)
    const int eb = g * EPG;
    for (int it = tid; it < EPG * 8; it += 256) {
        const int e = it >> 3, q = it & 7;
        const int sl = esrc[eb + e] - n0;
        const int dl = edst[eb + e] - n0;
        const float w = ew[eb + e];
        const uint2 u = *reinterpret_cast<const uint2*>(&y1s[sl * Y1S + q * 4]);
        float* a = acc + dl * ACS + q * 4;
        atomicAdd(a + 0, w * bfbits2f(u.x & 0xFFFFu));
        atomicAdd(a + 1, w * bfbits2f(u.x >> 16));
        atomicAdd(a + 2, w * bfbits2f(u.y & 0xFFFFu));
        atomicAdd(a + 3, w * bfbits2f(u.y >> 16));
    }
    __syncthreads();

    // Phase C
#pragma unroll
    for (int f = 0; f < FIN; ++f) wc[f] = W0[f * CH + c];
    const float bias = bc[c];
    for (int it = tid; it < NPG * CH; it += 256) {
        const int n = it >> 5;
        const float4* xr = reinterpret_cast<const float4*>(x + (size_t)(n0 + n) * FIN);
        float s = bias + acc[n * ACS + c];
#pragma unroll
        for (int f4 = 0; f4 < 16; ++f4) {
            const float4 v = xr[f4];
            s += v.x * wc[f4 * 4 + 0] + v.y * wc[f4 * 4 + 1]
               + v.z * wc[f4 * 4 + 2] + v.w * wc[f4 * 4 + 3];
        }
        s = (s > 0.f) ? s : expm1f(s);
        hy[(size_t)(n0 + n) * CH + c] = __float2bfloat16(s);
    }
}

// ---------------------------------------------------------------------------
// K0: Wd1 [8256][128] f32  ->  Wd1T [128][8256] bf16  (tiled via LDS)
// ---------------------------------------------------------------------------
__global__ __launch_bounds__(256) void wd1_transpose(
    const float* __restrict__ Wd1, unsigned short* __restrict__ Wd1T)
{
    __shared__ float st[128][65];
    const int tid = threadIdx.x;
    const int k0 = blockIdx.x * 64;
#pragma unroll
    for (int i = 0; i < 32; ++i) {
        const int idx = tid + i * 256;
        const int kl = idx >> 7, cc = idx & 127;
        st[cc][kl] = Wd1[(size_t)(k0 + kl) * HID + cc];
    }
    __syncthreads();
    const int cc = tid >> 1, gq = tid & 1;
#pragma unroll
    for (int i = 0; i < 8; ++i) {
        const int slot = gq + i * 2;   // 0..15
        const int ko = slot * 4;
        ushort4 o;
        o.x = f2bf(st[cc][ko + 0]);
        o.y = f2bf(st[cc][ko + 1]);
        o.z = f2bf(st[cc][ko + 2]);
        o.w = f2bf(st[cc][ko + 3]);
        *reinterpret_cast<ushort4*>(Wd1T + (size_t)cc * KTOT + k0 + ko) = o;
    }
}

// ---------------------------------------------------------------------------
// K2: GEMM1 via bf16 MFMA.  part[ks][m][c] = sum_{K chunk} h[m][k]*Wd1[k][c]
// grid (64 Mtiles, 8 ksplits); 4 waves/block, each wave: 16 rows x 32 cols.
// ---------------------------------------------------------------------------
__global__ __launch_bounds__(256) void gemm1_mfma(
    const unsigned short* __restrict__ h, const unsigned short* __restrict__ Wd1T,
    float* __restrict__ part)
{
    const int mt = blockIdx.x, ks = blockIdx.y;
    const int tid  = threadIdx.x;
    const int wave = tid >> 6, lane = tid & 63;
    const int m0 = mt * 16, nn0 = wave * 32;
    const int kb0 = ks * 258 / KSPL, kb1 = (ks + 1) * 258 / KSPL;   // 32-elem K blocks
    const int r  = lane & 15;        // A-row / B-col within frag
    const int kq = lane >> 4;        // k subgroup (8 elems each)

    f32x4 acc0 = {0.f, 0.f, 0.f, 0.f};
    f32x4 acc1 = {0.f, 0.f, 0.f, 0.f};
    const unsigned short* ap  = h    + (size_t)(m0 + r) * KTOT + kq * 8;
    const unsigned short* bp0 = Wd1T + (size_t)(nn0 + r) * KTOT + kq * 8;
    const unsigned short* bp1 = Wd1T + (size_t)(nn0 + 16 + r) * KTOT + kq * 8;

    for (int kb = kb0; kb < kb1; ++kb) {
        const int k = kb * 32;
        const bf16x8 a  = *reinterpret_cast<const bf16x8*>(ap + k);
        const bf16x8 b0 = *reinterpret_cast<const bf16x8*>(bp0 + k);
        const bf16x8 b1 = *reinterpret_cast<const bf16x8*>(bp1 + k);
        acc0 = __builtin_amdgcn_mfma_f32_16x16x32_bf16(a, b0, acc0, 0, 0, 0);
        acc1 = __builtin_amdgcn_mfma_f32_16x16x32_bf16(a, b1, acc1, 0, 0, 0);
    }

    float* p = part + ((size_t)ks * NB + m0) * HID + nn0;
#pragma unroll
    for (int rr = 0; rr < 4; ++rr) {
        const int row = kq * 4 + rr;   // C/D: col=lane&15, row=(lane>>4)*4+reg
        p[(size_t)row * HID + r]      = acc0[rr];
        p[(size_t)row * HID + 16 + r] = acc1[rr];
    }
}

// ---------------------------------------------------------------------------
// K3: MLP tail. 4 rows per block (one wave each).
// ---------------------------------------------------------------------------
__global__ __launch_bounds__(256) void mlp_tail(
    const float* __restrict__ part, const float* __restrict__ bd1,
    const float* __restrict__ Wd2, const float* __restrict__ bd2,
    const float* __restrict__ Wd3, const float* __restrict__ bd3,
    const float* __restrict__ Wd4, const float* __restrict__ bd4,
    float* __restrict__ out)
{
    __shared__ float w2[128 * 64];
    __shared__ float w3[64 * 32];
    __shared__ float w4[32];
    __shared__ float h1s[4][128];
    __shared__ float h2s[4][64];
    __shared__ float h3s[4][32];

    const int tid = threadIdx.x;
    for (int i = tid; i < 128 * 64; i += 256) w2[i] = Wd2[i];
    for (int i = tid; i < 64 * 32; i += 256)  w3[i] = Wd3[i];
    if (tid < 32) w4[tid] = Wd4[tid];

    const int r    = tid >> 6;
    const int lane = tid & 63;
    const int row  = blockIdx.x * 4 + r;

    float s0 = bd1[lane], s1 = bd1[lane + 64];
#pragma unroll
    for (int s = 0; s < KSPL; ++s) {
        const float* p = part + ((size_t)s * NB + row) * HID;
        s0 += p[lane];
        s1 += p[lane + 64];
    }
    h1s[r][lane]      = fmaxf(s0, 0.f);
    h1s[r][lane + 64] = fmaxf(s1, 0.f);
    __syncthreads();

    float s2 = bd2[lane];
#pragma unroll 8
    for (int k = 0; k < 128; ++k) s2 += h1s[r][k] * w2[k * 64 + lane];
    h2s[r][lane] = fmaxf(s2, 0.f);
    __syncthreads();

    if (lane < 32) {
        float s3 = bd3[lane];
#pragma unroll 8
        for (int k = 0; k < 64; ++k) s3 += h2s[r][k] * w3[k * 32 + lane];
        h3s[r][lane] = fmaxf(s3, 0.f);
    }
    __syncthreads();

    float p4 = (lane < 32) ? h3s[r][lane] * w4[lane] : 0.f;
#pragma unroll
    for (int off = 32; off > 0; off >>= 1) p4 += __shfl_down(p4, off, 64);
    if (lane == 0) out[row] = 1.f / (1.f + expf(-(p4 + bd4[0])));
}

// ---------------------------------------------------------------------------
extern "C" void kernel_launch(void* const* d_in, const int* in_sizes, int n_in,
                              void* d_out, int out_size, void* d_ws, size_t ws_size,
                              hipStream_t stream)
{
    const float* x    = (const float*)d_in[0];
    const int*   esrc = (const int*)d_in[1];
    const int*   edst = (const int*)d_in[2];
    const float* ew   = (const float*)d_in[3];
    const float* W0   = (const float*)d_in[4];
    const float* W1   = (const float*)d_in[5];
    const float* bc   = (const float*)d_in[6];
    const float* Wd1  = (const float*)d_in[7];
    const float* bd1  = (const float*)d_in[8];
    const float* Wd2  = (const float*)d_in[9];
    const float* bd2  = (const float*)d_in[10];
    const float* Wd3  = (const float*)d_in[11];
    const float* bd3  = (const float*)d_in[12];
    const float* Wd4  = (const float*)d_in[13];
    const float* bd4  = (const float*)d_in[14];
    float* out = (float*)d_out;

    // workspace: hy bf16 [NTOT*CH] | Wd1T bf16 [HID*KTOT] | part f32 [KSPL*NB*HID]
    char* wsb = (char*)d_ws;
    __hip_bfloat16* hy    = (__hip_bfloat16*)wsb;                       // 16,908,288 B
    unsigned short* wd1t  = (unsigned short*)(wsb + (size_t)NTOT * CH * 2);
    float*          part  = (float*)(wsb + (size_t)NTOT * CH * 2 + (size_t)HID * KTOT * 2);

    wd1_transpose<<<KTOT / 64, 256, 0, stream>>>(Wd1, wd1t);
    conv_fused<<<NB, 256, 0, stream>>>(x, esrc, edst, ew, W0, W1, bc, hy);
    gemm1_mfma<<<dim3(NB / 16, KSPL), 256, 0, stream>>>((const unsigned short*)hy, wd1t, part);
    mlp_tail<<<NB / 4, 256, 0, stream>>>(part, bd1, Wd2, bd2, Wd3, bd3, Wd4, bd4, out);
}

// Round 4
// 548.401 us; speedup vs baseline: 1.1380x; 1.0953x over previous
//
#include <hip/hip_runtime.h>
#include <hip/hip_bf16.h>

#define NPG 258
#define DEG 8
#define EPG 2064          // NPG*DEG
#define CH 32
#define FIN 64
#define NB 1024
#define NTOT (NB * NPG)   // 264192
#define HID 128
#define KTOT 8256         // NPG*CH
#define KSPL 32

typedef __attribute__((ext_vector_type(8))) short bf16x8;
typedef __attribute__((ext_vector_type(4))) float f32x4;

__device__ inline unsigned short f2bf(float f) {
    __hip_bfloat16 b = __float2bfloat16(f);
    return __builtin_bit_cast(unsigned short, b);
}
__device__ inline float bf2f(unsigned short u) {
    return __builtin_bit_cast(float, (unsigned)u << 16);
}
__device__ inline void cvt_split(const float4 a, const float4 b, bf16x8& hi, bf16x8& lo) {
    float f[8] = {a.x, a.y, a.z, a.w, b.x, b.y, b.z, b.w};
#pragma unroll
    for (int j = 0; j < 8; ++j) {
        unsigned short h = f2bf(f[j]);
        hi[j] = (short)h;
        lo[j] = (short)f2bf(f[j] - bf2f(h));
    }
}

// ---------------------------------------------------------------------------
// P0: WcatT_hi/lo [64 cols][64 k] bf16, col<32 from W0, col>=32 from W1.
// hi = bf16(w), lo = bf16(w - hi)  (split precision)
// ---------------------------------------------------------------------------
__global__ __launch_bounds__(256) void prep_wcat(
    const float* __restrict__ W0, const float* __restrict__ W1,
    unsigned short* __restrict__ Wh, unsigned short* __restrict__ Wl)
{
#pragma unroll
    for (int i = 0; i < 16; ++i) {
        const int idx = threadIdx.x + i * 256;
        const int c = idx >> 6, k = idx & 63;
        const float v = (c < 32) ? W0[k * CH + c] : W1[k * CH + (c - 32)];
        const unsigned short h = f2bf(v);
        Wh[c * 64 + k] = h;
        Wl[c * 64 + k] = f2bf(v - bf2f(h));
    }
}

// ---------------------------------------------------------------------------
// P1: Wd1 [8256][128] f32 -> Wd1T [128][8256] bf16
// ---------------------------------------------------------------------------
__global__ __launch_bounds__(256) void wd1_transpose(
    const float* __restrict__ Wd1, unsigned short* __restrict__ Wd1T)
{
    __shared__ float st[128][65];
    const int tid = threadIdx.x;
    const int k0 = blockIdx.x * 64;
#pragma unroll
    for (int i = 0; i < 32; ++i) {
        const int idx = tid + i * 256;
        const int kl = idx >> 7, cc = idx & 127;
        st[cc][kl] = Wd1[(size_t)(k0 + kl) * HID + cc];
    }
    __syncthreads();
    const int cc = tid >> 1, gq = tid & 1;
#pragma unroll
    for (int i = 0; i < 8; ++i) {
        const int ko = (gq + i * 2) * 4;
        ushort4 o;
        o.x = f2bf(st[cc][ko + 0]);
        o.y = f2bf(st[cc][ko + 1]);
        o.z = f2bf(st[cc][ko + 2]);
        o.w = f2bf(st[cc][ko + 3]);
        *reinterpret_cast<ushort4*>(Wd1T + (size_t)cc * KTOT + k0 + ko) = o;
    }
}

// ---------------------------------------------------------------------------
// K_A: y01 = x @ [W0|W1] via split-bf16 MFMA. BM=128, 4 waves x (32 rows, 64 cols).
// y0 (cols 0-31) f32, y1 (cols 32-63) bf16.
// ---------------------------------------------------------------------------
__global__ __launch_bounds__(256) void conv_gemm(
    const float* __restrict__ x, const unsigned short* __restrict__ Wh,
    const unsigned short* __restrict__ Wl,
    float* __restrict__ y0, unsigned short* __restrict__ y1)
{
    __shared__ unsigned short bsh[64 * 64];   // swizzled: granule g at g^(col&7)
    __shared__ unsigned short bsl[64 * 64];
    const int tid = threadIdx.x;
#pragma unroll
    for (int i = 0; i < 2; ++i) {
        const int s = tid + i * 256;          // 512 chunks of 16B
        const int col = s >> 3, o = s & 7;
        const int so = o ^ (col & 7);
        *reinterpret_cast<uint4*>(&bsh[col * 64 + so * 8]) =
            *reinterpret_cast<const uint4*>(&Wh[col * 64 + o * 8]);
        *reinterpret_cast<uint4*>(&bsl[col * 64 + so * 8]) =
            *reinterpret_cast<const uint4*>(&Wl[col * 64 + o * 8]);
    }
    __syncthreads();

    const int w = tid >> 6, lane = tid & 63;
    const int r = lane & 15, kq = lane >> 4;
    const long rowbase = (long)blockIdx.x * 128 + w * 32;

    // A fragments from global (f32 -> split bf16)
    bf16x8 ah[2][2], al[2][2];
#pragma unroll
    for (int mt = 0; mt < 2; ++mt)
#pragma unroll
        for (int ks = 0; ks < 2; ++ks) {
            const float* xp = x + (rowbase + mt * 16 + r) * FIN + ks * 32 + kq * 8;
            const float4 p0 = *reinterpret_cast<const float4*>(xp);
            const float4 p1 = *reinterpret_cast<const float4*>(xp + 4);
            cvt_split(p0, p1, ah[mt][ks], al[mt][ks]);
        }

    f32x4 acc[2][4];
#pragma unroll
    for (int mt = 0; mt < 2; ++mt)
#pragma unroll
        for (int nt = 0; nt < 4; ++nt) acc[mt][nt] = f32x4{0.f, 0.f, 0.f, 0.f};

#pragma unroll
    for (int nt = 0; nt < 4; ++nt) {
        const int col = nt * 16 + r;
        const int cs = col & 7;
#pragma unroll
        for (int ks = 0; ks < 2; ++ks) {
            const int g = (ks * 4 + kq) ^ cs;
            const bf16x8 bh = *reinterpret_cast<const bf16x8*>(&bsh[col * 64 + g * 8]);
            const bf16x8 bl = *reinterpret_cast<const bf16x8*>(&bsl[col * 64 + g * 8]);
#pragma unroll
            for (int mt = 0; mt < 2; ++mt) {
                acc[mt][nt] = __builtin_amdgcn_mfma_f32_16x16x32_bf16(ah[mt][ks], bh, acc[mt][nt], 0, 0, 0);
                acc[mt][nt] = __builtin_amdgcn_mfma_f32_16x16x32_bf16(ah[mt][ks], bl, acc[mt][nt], 0, 0, 0);
                acc[mt][nt] = __builtin_amdgcn_mfma_f32_16x16x32_bf16(al[mt][ks], bh, acc[mt][nt], 0, 0, 0);
            }
        }
    }

    // epilogue: C/D col=lane&15, row=(lane>>4)*4+rr (m89-verified)
#pragma unroll
    for (int mt = 0; mt < 2; ++mt)
#pragma unroll
        for (int rr = 0; rr < 4; ++rr) {
            const long rg = rowbase + mt * 16 + kq * 4 + rr;
            y0[rg * CH + r]      = acc[mt][0][rr];
            y0[rg * CH + 16 + r] = acc[mt][1][rr];
            y1[rg * CH + r]      = f2bf(acc[mt][2][rr]);
            y1[rg * CH + 16 + r] = f2bf(acc[mt][3][rr]);
        }
}

// ---------------------------------------------------------------------------
// K_B: per-graph scatter + bias + elu. One block/graph, 256 thr.
// acc stride 32 + one channel per lane -> bank = c (conflict-free atomics).
// ---------------------------------------------------------------------------
__global__ __launch_bounds__(256) void conv_scatter(
    const int* __restrict__ esrc, const int* __restrict__ edst,
    const float* __restrict__ ew, const float* __restrict__ y0,
    const unsigned short* __restrict__ y1, const float* __restrict__ bc,
    unsigned short* __restrict__ h)
{
    __shared__ unsigned short y1s[NPG * CH];   // 16512 B
    __shared__ unsigned int   e_sd[EPG];       // 8256 B
    __shared__ float          e_w[EPG];        // 8256 B
    __shared__ float          acc[NPG * CH];   // 33024 B   (total 66048 B)
    const int g = blockIdx.x, tid = threadIdx.x;
    const int n0 = g * NPG;
    const long eb = (long)g * EPG;
    const long qb = (long)g * (NPG * CH);

    // stage edges (packed local src|dst, weight)
#pragma unroll
    for (int i = 0; i < 9; ++i) {
        const int e = tid + i * 256;
        if (e < EPG) {
            const int sl = esrc[eb + e] - n0;
            const int dl = edst[eb + e] - n0;
            e_sd[e] = (unsigned)sl | ((unsigned)dl << 16);
            e_w[e] = ew[eb + e];
        }
    }
    // stage y1 (linear bf16 copy) + zero acc
#pragma unroll
    for (int i = 0; i < 9; ++i) {
        const int q = tid + i * 256;
        if (q < 2064) {
            *reinterpret_cast<ushort4*>(&y1s[q * 4]) =
                *reinterpret_cast<const ushort4*>(&y1[qb + q * 4]);
            *reinterpret_cast<float4*>(&acc[q * 4]) = float4{0.f, 0.f, 0.f, 0.f};
        }
    }
    __syncthreads();

    // scatter: group (tid>>5) walks 258 edges, lane channel c = tid&31
    const int c = tid & 31;
    const int base = (tid >> 5) * 258;
#pragma unroll 2
    for (int i = 0; i < 258; ++i) {
        const unsigned u = e_sd[base + i];
        const float w = e_w[base + i];
        const int sl = u & 0xFFFFu, dl = u >> 16;
        atomicAdd(&acc[dl * CH + c], w * bf2f(y1s[sl * CH + c]));
    }
    __syncthreads();

    // finalize: h = elu(y0 + bias + acc) -> bf16
#pragma unroll
    for (int i = 0; i < 9; ++i) {
        const int q = tid + i * 256;
        if (q < 2064) {
            const float4 a = *reinterpret_cast<const float4*>(&acc[q * 4]);
            const float4 z = *reinterpret_cast<const float4*>(&y0[qb + q * 4]);
            const float4 b = *reinterpret_cast<const float4*>(&bc[(q & 7) * 4]);
            float s0 = z.x + b.x + a.x, s1 = z.y + b.y + a.y;
            float s2 = z.z + b.z + a.z, s3 = z.w + b.w + a.w;
            s0 = (s0 > 0.f) ? s0 : expm1f(s0);
            s1 = (s1 > 0.f) ? s1 : expm1f(s1);
            s2 = (s2 > 0.f) ? s2 : expm1f(s2);
            s3 = (s3 > 0.f) ? s3 : expm1f(s3);
            ushort4 o{f2bf(s0), f2bf(s1), f2bf(s2), f2bf(s3)};
            *reinterpret_cast<ushort4*>(&h[qb + q * 4]) = o;
        }
    }
}

// ---------------------------------------------------------------------------
// K2: GEMM1 partials, direct-from-global MFMA. Wave tile 64 rows x 32 cols.
// grid (16 mtiles, 32 ksplits). part[ks][m][c] f32.
// ---------------------------------------------------------------------------
__global__ __launch_bounds__(256) void gemm1(
    const unsigned short* __restrict__ h, const unsigned short* __restrict__ Wd1T,
    float* __restrict__ part)
{
    const int tid = threadIdx.x, w = tid >> 6, lane = tid & 63;
    const int r = lane & 15, kq = lane >> 4;
    const long m0 = (long)blockIdx.x * 64;
    const int ks = blockIdx.y;
    const int kb0 = ks * 258 / KSPL, kb1 = (ks + 1) * 258 / KSPL;
    const int c0 = w * 32;

    f32x4 acc[4][2];
#pragma unroll
    for (int a = 0; a < 4; ++a)
#pragma unroll
        for (int b = 0; b < 2; ++b) acc[a][b] = f32x4{0.f, 0.f, 0.f, 0.f};

    const unsigned short* ap = h    + (m0 + r) * KTOT + kq * 8;
    const unsigned short* bp = Wd1T + (long)(c0 + r) * KTOT + kq * 8;

    for (int kb = kb0; kb < kb1; ++kb) {
        const int k = kb * 32;
        const bf16x8 b0 = *reinterpret_cast<const bf16x8*>(bp + k);
        const bf16x8 b1 = *reinterpret_cast<const bf16x8*>(bp + 16 * KTOT + k);
#pragma unroll
        for (int mt = 0; mt < 4; ++mt) {
            const bf16x8 a = *reinterpret_cast<const bf16x8*>(ap + mt * 16 * KTOT + k);
            acc[mt][0] = __builtin_amdgcn_mfma_f32_16x16x32_bf16(a, b0, acc[mt][0], 0, 0, 0);
            acc[mt][1] = __builtin_amdgcn_mfma_f32_16x16x32_bf16(a, b1, acc[mt][1], 0, 0, 0);
        }
    }

    float* p = part + ((long)ks * NB + m0) * HID + c0;
#pragma unroll
    for (int mt = 0; mt < 4; ++mt)
#pragma unroll
        for (int rr = 0; rr < 4; ++rr) {
            const int row = mt * 16 + kq * 4 + rr;
            p[(long)row * HID + r]      = acc[mt][0][rr];
            p[(long)row * HID + 16 + r] = acc[mt][1][rr];
        }
}

// ---------------------------------------------------------------------------
// K3: MLP tail. 4 rows/block (1 wave each).
// ---------------------------------------------------------------------------
__global__ __launch_bounds__(256) void mlp_tail(
    const float* __restrict__ part, const float* __restrict__ bd1,
    const float* __restrict__ Wd2, const float* __restrict__ bd2,
    const float* __restrict__ Wd3, const float* __restrict__ bd3,
    const float* __restrict__ Wd4, const float* __restrict__ bd4,
    float* __restrict__ out)
{
    __shared__ float w2[128 * 64];
    __shared__ float w3[64 * 32];
    __shared__ float w4[32];
    __shared__ float h1s[4][128];
    __shared__ float h2s[4][64];
    __shared__ float h3s[4][32];

    const int tid = threadIdx.x;
    for (int i = tid; i < 128 * 64; i += 256) w2[i] = Wd2[i];
    for (int i = tid; i < 64 * 32; i += 256)  w3[i] = Wd3[i];
    if (tid < 32) w4[tid] = Wd4[tid];

    const int r = tid >> 6;
    const int lane = tid & 63;
    const int row = blockIdx.x * 4 + r;

    float s0 = bd1[lane], s1 = bd1[lane + 64];
#pragma unroll 8
    for (int s = 0; s < KSPL; ++s) {
        const float* p = part + ((long)s * NB + row) * HID;
        s0 += p[lane];
        s1 += p[lane + 64];
    }
    h1s[r][lane]      = fmaxf(s0, 0.f);
    h1s[r][lane + 64] = fmaxf(s1, 0.f);
    __syncthreads();

    float s2 = bd2[lane];
#pragma unroll 8
    for (int k = 0; k < 128; ++k) s2 += h1s[r][k] * w2[k * 64 + lane];
    h2s[r][lane] = fmaxf(s2, 0.f);
    __syncthreads();

    if (lane < 32) {
        float s3 = bd3[lane];
#pragma unroll 8
        for (int k = 0; k < 64; ++k) s3 += h2s[r][k] * w3[k * 32 + lane];
        h3s[r][lane] = fmaxf(s3, 0.f);
    }
    __syncthreads();

    float p4 = (lane < 32) ? h3s[r][lane] * w4[lane] : 0.f;
#pragma unroll
    for (int off = 32; off > 0; off >>= 1) p4 += __shfl_down(p4, off, 64);
    if (lane == 0) out[row] = 1.f / (1.f + expf(-(p4 + bd4[0])));
}

// ---------------------------------------------------------------------------
extern "C" void kernel_launch(void* const* d_in, const int* in_sizes, int n_in,
                              void* d_out, int out_size, void* d_ws, size_t ws_size,
                              hipStream_t stream)
{
    const float* x    = (const float*)d_in[0];
    const int*   esrc = (const int*)d_in[1];
    const int*   edst = (const int*)d_in[2];
    const float* ew   = (const float*)d_in[3];
    const float* W0   = (const float*)d_in[4];
    const float* W1   = (const float*)d_in[5];
    const float* bc   = (const float*)d_in[6];
    const float* Wd1  = (const float*)d_in[7];
    const float* bd1  = (const float*)d_in[8];
    const float* Wd2  = (const float*)d_in[9];
    const float* bd2  = (const float*)d_in[10];
    const float* Wd3  = (const float*)d_in[11];
    const float* bd3  = (const float*)d_in[12];
    const float* Wd4  = (const float*)d_in[13];
    const float* bd4  = (const float*)d_in[14];
    float* out = (float*)d_out;

    // ws layout (bytes):
    //   h    bf16 [NTOT*CH]        @ 0          (16,908,288)
    //   wd1t bf16 [HID*KTOT]       @ 16908288   ( 2,113,536)
    //   wch  bf16 [64*64]          @ 19021824   (     8,192)
    //   wcl  bf16 [64*64]          @ 19030016   (     8,192)
    //   y0   f32  [NTOT*CH]        @ 19038208   (33,816,576)  <- part aliases here
    //   y1   bf16 [NTOT*CH]        @ 52854784   (16,908,288)  -> total 69,763,072
    char* wsb = (char*)d_ws;
    unsigned short* h    = (unsigned short*)wsb;
    unsigned short* wd1t = (unsigned short*)(wsb + 16908288);
    unsigned short* wch  = (unsigned short*)(wsb + 19021824);
    unsigned short* wcl  = (unsigned short*)(wsb + 19030016);
    float*          y0   = (float*)(wsb + 19038208);
    unsigned short* y1   = (unsigned short*)(wsb + 52854784);
    float*          part = (float*)(wsb + 19038208);   // reuse y0 after conv_scatter

    prep_wcat<<<1, 256, 0, stream>>>(W0, W1, wch, wcl);
    wd1_transpose<<<KTOT / 64, 256, 0, stream>>>(Wd1, wd1t);
    conv_gemm<<<NTOT / 128, 256, 0, stream>>>(x, wch, wcl, y0, y1);
    conv_scatter<<<NB, 256, 0, stream>>>(esrc, edst, ew, y0, y1, bc, h);
    gemm1<<<dim3(NB / 64, KSPL), 256, 0, stream>>>(h, wd1t, part);
    mlp_tail<<<NB / 4, 256, 0, stream>>>(part, bd1, Wd2, bd2, Wd3, bd3, Wd4, bd4, out);
}

// Round 7
// 540.530 us; speedup vs baseline: 1.1545x; 1.0146x over previous
//
#include <hip/hip_runtime.h>
#include <hip/hip_bf16.h>

#define NPG 258
#define DEG 8
#define EPG 2064          // NPG*DEG
#define CH 32
#define FIN 64
#define NB 1024
#define NTOT (NB * NPG)   // 264192
#define HID 128
#define KTOT 8256         // NPG*CH
#define KSPL 32
#define ACS 9             // acc LDS stride (f32) per 8-channel slice

typedef __attribute__((ext_vector_type(8))) short bf16x8;
typedef __attribute__((ext_vector_type(4))) float f32x4;

__device__ inline unsigned short f2bf(float f) {
    __hip_bfloat16 b = __float2bfloat16(f);
    return __builtin_bit_cast(unsigned short, b);
}
__device__ inline float bf2f(unsigned short u) {
    return __builtin_bit_cast(float, (unsigned)u << 16);
}
__device__ inline void cvt_split(const float4 a, const float4 b, bf16x8& hi, bf16x8& lo) {
    float f[8] = {a.x, a.y, a.z, a.w, b.x, b.y, b.z, b.w};
#pragma unroll
    for (int j = 0; j < 8; ++j) {
        unsigned short h = f2bf(f[j]);
        hi[j] = (short)h;
        lo[j] = (short)f2bf(f[j] - bf2f(h));
    }
}

// ---------------------------------------------------------------------------
// P0: WcatT_hi/lo [64 cols][64 k] bf16, col<32 from W0, col>=32 from W1.
// ---------------------------------------------------------------------------
__global__ __launch_bounds__(256) void prep_wcat(
    const float* __restrict__ W0, const float* __restrict__ W1,
    unsigned short* __restrict__ Wh, unsigned short* __restrict__ Wl)
{
#pragma unroll
    for (int i = 0; i < 16; ++i) {
        const int idx = threadIdx.x + i * 256;
        const int c = idx >> 6, k = idx & 63;
        const float v = (c < 32) ? W0[k * CH + c] : W1[k * CH + (c - 32)];
        const unsigned short h = f2bf(v);
        Wh[c * 64 + k] = h;
        Wl[c * 64 + k] = f2bf(v - bf2f(h));
    }
}

// ---------------------------------------------------------------------------
// P1: Wd1 [8256][128] f32 -> Wd1T [128][8256] bf16
// ---------------------------------------------------------------------------
__global__ __launch_bounds__(256) void wd1_transpose(
    const float* __restrict__ Wd1, unsigned short* __restrict__ Wd1T)
{
    __shared__ float st[128][65];
    const int tid = threadIdx.x;
    const int k0 = blockIdx.x * 64;
#pragma unroll
    for (int i = 0; i < 32; ++i) {
        const int idx = tid + i * 256;
        const int kl = idx >> 7, cc = idx & 127;
        st[cc][kl] = Wd1[(size_t)(k0 + kl) * HID + cc];
    }
    __syncthreads();
    const int cc = tid >> 1, gq = tid & 1;
#pragma unroll
    for (int i = 0; i < 8; ++i) {
        const int ko = (gq + i * 2) * 4;
        ushort4 o;
        o.x = f2bf(st[cc][ko + 0]);
        o.y = f2bf(st[cc][ko + 1]);
        o.z = f2bf(st[cc][ko + 2]);
        o.w = f2bf(st[cc][ko + 3]);
        *reinterpret_cast<ushort4*>(Wd1T + (size_t)cc * KTOT + k0 + ko) = o;
    }
}

// ---------------------------------------------------------------------------
// K_A: y01 = x @ [W0|W1] via split-bf16 MFMA. BM=128, 4 waves x (32 rows, 64 cols).
// ---------------------------------------------------------------------------
__global__ __launch_bounds__(256) void conv_gemm(
    const float* __restrict__ x, const unsigned short* __restrict__ Wh,
    const unsigned short* __restrict__ Wl,
    float* __restrict__ y0, unsigned short* __restrict__ y1)
{
    __shared__ unsigned short bsh[64 * 64];   // swizzled: granule g at g^(col&7)
    __shared__ unsigned short bsl[64 * 64];
    const int tid = threadIdx.x;
#pragma unroll
    for (int i = 0; i < 2; ++i) {
        const int s = tid + i * 256;
        const int col = s >> 3, o = s & 7;
        const int so = o ^ (col & 7);
        *reinterpret_cast<uint4*>(&bsh[col * 64 + so * 8]) =
            *reinterpret_cast<const uint4*>(&Wh[col * 64 + o * 8]);
        *reinterpret_cast<uint4*>(&bsl[col * 64 + so * 8]) =
            *reinterpret_cast<const uint4*>(&Wl[col * 64 + o * 8]);
    }
    __syncthreads();

    const int w = tid >> 6, lane = tid & 63;
    const int r = lane & 15, kq = lane >> 4;
    const long rowbase = (long)blockIdx.x * 128 + w * 32;

    bf16x8 ah[2][2], al[2][2];
#pragma unroll
    for (int mt = 0; mt < 2; ++mt)
#pragma unroll
        for (int ks = 0; ks < 2; ++ks) {
            const float* xp = x + (rowbase + mt * 16 + r) * FIN + ks * 32 + kq * 8;
            const float4 p0 = *reinterpret_cast<const float4*>(xp);
            const float4 p1 = *reinterpret_cast<const float4*>(xp + 4);
            cvt_split(p0, p1, ah[mt][ks], al[mt][ks]);
        }

    f32x4 acc[2][4];
#pragma unroll
    for (int mt = 0; mt < 2; ++mt)
#pragma unroll
        for (int nt = 0; nt < 4; ++nt) acc[mt][nt] = f32x4{0.f, 0.f, 0.f, 0.f};

#pragma unroll
    for (int nt = 0; nt < 4; ++nt) {
        const int col = nt * 16 + r;
        const int cs = col & 7;
#pragma unroll
        for (int ks = 0; ks < 2; ++ks) {
            const int g = (ks * 4 + kq) ^ cs;
            const bf16x8 bh = *reinterpret_cast<const bf16x8*>(&bsh[col * 64 + g * 8]);
            const bf16x8 bl = *reinterpret_cast<const bf16x8*>(&bsl[col * 64 + g * 8]);
#pragma unroll
            for (int mt = 0; mt < 2; ++mt) {
                acc[mt][nt] = __builtin_amdgcn_mfma_f32_16x16x32_bf16(ah[mt][ks], bh, acc[mt][nt], 0, 0, 0);
                acc[mt][nt] = __builtin_amdgcn_mfma_f32_16x16x32_bf16(ah[mt][ks], bl, acc[mt][nt], 0, 0, 0);
                acc[mt][nt] = __builtin_amdgcn_mfma_f32_16x16x32_bf16(al[mt][ks], bh, acc[mt][nt], 0, 0, 0);
            }
        }
    }

#pragma unroll
    for (int mt = 0; mt < 2; ++mt)
#pragma unroll
        for (int rr = 0; rr < 4; ++rr) {
            const long rg = rowbase + mt * 16 + kq * 4 + rr;
            y0[rg * CH + r]      = acc[mt][0][rr];
            y0[rg * CH + 16 + r] = acc[mt][1][rr];
            y1[rg * CH + r]      = f2bf(acc[mt][2][rr]);
            y1[rg * CH + 16 + r] = f2bf(acc[mt][3][rr]);
        }
}

// ---------------------------------------------------------------------------
// K_B: scatter + bias + elu. FOUR blocks per graph (8 channels each).
// 32 groups x 8 lanes; group walks edges strided by 32 (2-stage pipeline).
// ---------------------------------------------------------------------------
__global__ __launch_bounds__(256) void conv_scatter(
    const int* __restrict__ esrc, const int* __restrict__ edst,
    const float* __restrict__ ew, const float* __restrict__ y0,
    const unsigned short* __restrict__ y1, const float* __restrict__ bc,
    unsigned short* __restrict__ h)
{
    __shared__ unsigned int   e_sd[EPG];        // 8256 B
    __shared__ float          e_w[EPG];         // 8256 B
    __shared__ unsigned short y1q[NPG * 8];     // 4128 B
    __shared__ float          accq[NPG * ACS];  // 9288 B  (~30 KB total)
    const int g   = blockIdx.x >> 2;
    const int c0  = (blockIdx.x & 3) * 8;
    const int tid = threadIdx.x;
    const int n0  = g * NPG;
    const long eb = (long)g * EPG;
    const long qb = (long)g * (NPG * CH);

    // stage edges (packed local src|dst, weight)
#pragma unroll
    for (int i = 0; i < 9; ++i) {
        const int e = tid + i * 256;
        if (e < EPG) {
            const int sl = esrc[eb + e] - n0;
            const int dl = edst[eb + e] - n0;
            e_sd[e] = (unsigned)sl | ((unsigned)dl << 16);
            e_w[e] = ew[eb + e];
        }
    }
    // stage y1 channel-octet (ushort4 per task), zero acc
#pragma unroll
    for (int i = 0; i < 3; ++i) {
        const int q = tid + i * 256;            // 516 tasks: node n, half hh
        if (q < 516) {
            const int n = q >> 1, hh = q & 1;
            *reinterpret_cast<ushort4*>(&y1q[n * 8 + hh * 4]) =
                *reinterpret_cast<const ushort4*>(&y1[qb + (long)n * CH + c0 + hh * 4]);
        }
    }
    for (int i = tid; i < NPG * ACS; i += 256) accq[i] = 0.f;
    __syncthreads();

    // scatter: group gid = tid>>3 (32 groups), lane channel c = tid&7
    const int c = tid & 7;
    const int gid = tid >> 3;
    {
        int i = gid;
        unsigned u = e_sd[i];
        float w = e_w[i];
        for (i += 32; i < EPG; i += 32) {
            const unsigned u2 = e_sd[i];
            const float w2 = e_w[i];
            const int sl = u & 0xFFFFu, dl = u >> 16;
            atomicAdd(&accq[dl * ACS + c], w * bf2f(y1q[sl * 8 + c]));
            u = u2; w = w2;
        }
        const int sl = u & 0xFFFFu, dl = u >> 16;
        atomicAdd(&accq[dl * ACS + c], w * bf2f(y1q[sl * 8 + c]));
    }
    __syncthreads();

    // finalize: h[:, c0:c0+8] = elu(y0 + bias + acc) -> bf16
#pragma unroll
    for (int i = 0; i < 3; ++i) {
        const int q = tid + i * 256;
        if (q < 516) {
            const int n = q >> 1, hh = q & 1;
            const float4 z = *reinterpret_cast<const float4*>(&y0[qb + (long)n * CH + c0 + hh * 4]);
            const float4 b = *reinterpret_cast<const float4*>(&bc[c0 + hh * 4]);
            const float* a = &accq[n * ACS + hh * 4];
            float s0 = z.x + b.x + a[0], s1 = z.y + b.y + a[1];
            float s2 = z.z + b.z + a[2], s3 = z.w + b.w + a[3];
            s0 = (s0 > 0.f) ? s0 : expm1f(s0);
            s1 = (s1 > 0.f) ? s1 : expm1f(s1);
            s2 = (s2 > 0.f) ? s2 : expm1f(s2);
            s3 = (s3 > 0.f) ? s3 : expm1f(s3);
            ushort4 o{f2bf(s0), f2bf(s1), f2bf(s2), f2bf(s3)};
            *reinterpret_cast<ushort4*>(&h[qb + (long)n * CH + c0 + hh * 4]) = o;
        }
    }
}

// ---------------------------------------------------------------------------
// K2: GEMM1 partials, direct-from-global MFMA. Wave tile 64 rows x 32 cols.
// ---------------------------------------------------------------------------
__global__ __launch_bounds__(256) void gemm1(
    const unsigned short* __restrict__ h, const unsigned short* __restrict__ Wd1T,
    float* __restrict__ part)
{
    const int tid = threadIdx.x, w = tid >> 6, lane = tid & 63;
    const int r = lane & 15, kq = lane >> 4;
    const long m0 = (long)blockIdx.x * 64;
    const int ks = blockIdx.y;
    const int kb0 = ks * 258 / KSPL, kb1 = (ks + 1) * 258 / KSPL;
    const int c0 = w * 32;

    f32x4 acc[4][2];
#pragma unroll
    for (int a = 0; a < 4; ++a)
#pragma unroll
        for (int b = 0; b < 2; ++b) acc[a][b] = f32x4{0.f, 0.f, 0.f, 0.f};

    const unsigned short* ap = h    + (m0 + r) * KTOT + kq * 8;
    const unsigned short* bp = Wd1T + (long)(c0 + r) * KTOT + kq * 8;

    for (int kb = kb0; kb < kb1; ++kb) {
        const int k = kb * 32;
        const bf16x8 b0 = *reinterpret_cast<const bf16x8*>(bp + k);
        const bf16x8 b1 = *reinterpret_cast<const bf16x8*>(bp + 16 * KTOT + k);
#pragma unroll
        for (int mt = 0; mt < 4; ++mt) {
            const bf16x8 a = *reinterpret_cast<const bf16x8*>(ap + mt * 16 * KTOT + k);
            acc[mt][0] = __builtin_amdgcn_mfma_f32_16x16x32_bf16(a, b0, acc[mt][0], 0, 0, 0);
            acc[mt][1] = __builtin_amdgcn_mfma_f32_16x16x32_bf16(a, b1, acc[mt][1], 0, 0, 0);
        }
    }

    float* p = part + ((long)ks * NB + m0) * HID + c0;
#pragma unroll
    for (int mt = 0; mt < 4; ++mt)
#pragma unroll
        for (int rr = 0; rr < 4; ++rr) {
            const int row = mt * 16 + kq * 4 + rr;
            p[(long)row * HID + r]      = acc[mt][0][rr];
            p[(long)row * HID + 16 + r] = acc[mt][1][rr];
        }
}

// ---------------------------------------------------------------------------
// K3: MLP tail. 4 rows/block (1 wave each).
// ---------------------------------------------------------------------------
__global__ __launch_bounds__(256) void mlp_tail(
    const float* __restrict__ part, const float* __restrict__ bd1,
    const float* __restrict__ Wd2, const float* __restrict__ bd2,
    const float* __restrict__ Wd3, const float* __restrict__ bd3,
    const float* __restrict__ Wd4, const float* __restrict__ bd4,
    float* __restrict__ out)
{
    __shared__ float w2[128 * 64];
    __shared__ float w3[64 * 32];
    __shared__ float w4[32];
    __shared__ float h1s[4][128];
    __shared__ float h2s[4][64];
    __shared__ float h3s[4][32];

    const int tid = threadIdx.x;
    for (int i = tid; i < 128 * 64; i += 256) w2[i] = Wd2[i];
    for (int i = tid; i < 64 * 32; i += 256)  w3[i] = Wd3[i];
    if (tid < 32) w4[tid] = Wd4[tid];

    const int r = tid >> 6;
    const int lane = tid & 63;
    const int row = blockIdx.x * 4 + r;

    float s0 = bd1[lane], s1 = bd1[lane + 64];
#pragma unroll 8
    for (int s = 0; s < KSPL; ++s) {
        const float* p = part + ((long)s * NB + row) * HID;
        s0 += p[lane];
        s1 += p[lane + 64];
    }
    h1s[r][lane]      = fmaxf(s0, 0.f);
    h1s[r][lane + 64] = fmaxf(s1, 0.f);
    __syncthreads();

    float s2 = bd2[lane];
#pragma unroll 8
    for (int k = 0; k < 128; ++k) s2 += h1s[r][k] * w2[k * 64 + lane];
    h2s[r][lane] = fmaxf(s2, 0.f);
    __syncthreads();

    if (lane < 32) {
        float s3 = bd3[lane];
#pragma unroll 8
        for (int k = 0; k < 64; ++k) s3 += h2s[r][k] * w3[k * 32 + lane];
        h3s[r][lane] = fmaxf(s3, 0.f);
    }
    __syncthreads();

    float p4 = (lane < 32) ? h3s[r][lane] * w4[lane] : 0.f;
#pragma unroll
    for (int off = 32; off > 0; off >>= 1) p4 += __shfl_down(p4, off, 64);
    if (lane == 0) out[row] = 1.f / (1.f + expf(-(p4 + bd4[0])));
}

// ---------------------------------------------------------------------------
extern "C" void kernel_launch(void* const* d_in, const int* in_sizes, int n_in,
                              void* d_out, int out_size, void* d_ws, size_t ws_size,
                              hipStream_t stream)
{
    const float* x    = (const float*)d_in[0];
    const int*   esrc = (const int*)d_in[1];
    const int*   edst = (const int*)d_in[2];
    const float* ew   = (const float*)d_in[3];
    const float* W0   = (const float*)d_in[4];
    const float* W1   = (const float*)d_in[5];
    const float* bc   = (const float*)d_in[6];
    const float* Wd1  = (const float*)d_in[7];
    const float* bd1  = (const float*)d_in[8];
    const float* Wd2  = (const float*)d_in[9];
    const float* bd2  = (const float*)d_in[10];
    const float* Wd3  = (const float*)d_in[11];
    const float* bd3  = (const float*)d_in[12];
    const float* Wd4  = (const float*)d_in[13];
    const float* bd4  = (const float*)d_in[14];
    float* out = (float*)d_out;

    char* wsb = (char*)d_ws;
    unsigned short* h    = (unsigned short*)wsb;                 // 16,908,288 B
    unsigned short* wd1t = (unsigned short*)(wsb + 16908288);    //  2,113,536 B
    unsigned short* wch  = (unsigned short*)(wsb + 19021824);
    unsigned short* wcl  = (unsigned short*)(wsb + 19030016);
    float*          y0   = (float*)(wsb + 19038208);             // 33,816,576 B
    unsigned short* y1   = (unsigned short*)(wsb + 52854784);    // 16,908,288 B
    float*          part = (float*)(wsb + 19038208);             // reuse y0

    prep_wcat<<<1, 256, 0, stream>>>(W0, W1, wch, wcl);
    wd1_transpose<<<KTOT / 64, 256, 0, stream>>>(Wd1, wd1t);
    conv_gemm<<<NTOT / 128, 256, 0, stream>>>(x, wch, wcl, y0, y1);
    conv_scatter<<<NB * 4, 256, 0, stream>>>(esrc, edst, ew, y0, y1, bc, h);
    gemm1<<<dim3(NB / 64, KSPL), 256, 0, stream>>>(h, wd1t, part);
    mlp_tail<<<NB / 4, 256, 0, stream>>>(part, bd1, Wd2, bd2, Wd3, bd3, Wd4, bd4, out);
}

// Round 8
// 230.471 us; speedup vs baseline: 2.7077x; 2.3453x over previous
//
#include <hip/hip_runtime.h>
#include <hip/hip_bf16.h>

#define NPG 258
#define DEG 8
#define EPG 2064          // NPG*DEG
#define CH 32
#define FIN 64
#define NB 1024
#define NTOT (NB * NPG)   // 264192
#define HID 128
#define KTOT 8256         // NPG*CH
#define KSPL 32

typedef __attribute__((ext_vector_type(8))) short bf16x8;
typedef __attribute__((ext_vector_type(4))) float f32x4;

__device__ inline unsigned short f2bf(float f) {
    __hip_bfloat16 b = __float2bfloat16(f);
    return __builtin_bit_cast(unsigned short, b);
}
__device__ inline float bf2f(unsigned short u) {
    return __builtin_bit_cast(float, (unsigned)u << 16);
}
__device__ inline void cvt_split(const float4 a, const float4 b, bf16x8& hi, bf16x8& lo) {
    float f[8] = {a.x, a.y, a.z, a.w, b.x, b.y, b.z, b.w};
#pragma unroll
    for (int j = 0; j < 8; ++j) {
        unsigned short h = f2bf(f[j]);
        hi[j] = (short)h;
        lo[j] = (short)f2bf(f[j] - bf2f(h));
    }
}

// ---------------------------------------------------------------------------
// P0: WcatT_hi/lo [64 cols][64 k] bf16, col<32 from W0, col>=32 from W1.
// ---------------------------------------------------------------------------
__global__ __launch_bounds__(256) void prep_wcat(
    const float* __restrict__ W0, const float* __restrict__ W1,
    unsigned short* __restrict__ Wh, unsigned short* __restrict__ Wl)
{
#pragma unroll
    for (int i = 0; i < 16; ++i) {
        const int idx = threadIdx.x + i * 256;
        const int c = idx >> 6, k = idx & 63;
        const float v = (c < 32) ? W0[k * CH + c] : W1[k * CH + (c - 32)];
        const unsigned short h = f2bf(v);
        Wh[c * 64 + k] = h;
        Wl[c * 64 + k] = f2bf(v - bf2f(h));
    }
}

// ---------------------------------------------------------------------------
// P1: Wd1 [8256][128] f32 -> Wd1T [128][8256] bf16
// ---------------------------------------------------------------------------
__global__ __launch_bounds__(256) void wd1_transpose(
    const float* __restrict__ Wd1, unsigned short* __restrict__ Wd1T)
{
    __shared__ float st[128][65];
    const int tid = threadIdx.x;
    const int k0 = blockIdx.x * 64;
#pragma unroll
    for (int i = 0; i < 32; ++i) {
        const int idx = tid + i * 256;
        const int kl = idx >> 7, cc = idx & 127;
        st[cc][kl] = Wd1[(size_t)(k0 + kl) * HID + cc];
    }
    __syncthreads();
    const int cc = tid >> 1, gq = tid & 1;
#pragma unroll
    for (int i = 0; i < 8; ++i) {
        const int ko = (gq + i * 2) * 4;
        ushort4 o;
        o.x = f2bf(st[cc][ko + 0]);
        o.y = f2bf(st[cc][ko + 1]);
        o.z = f2bf(st[cc][ko + 2]);
        o.w = f2bf(st[cc][ko + 3]);
        *reinterpret_cast<ushort4*>(Wd1T + (size_t)cc * KTOT + k0 + ko) = o;
    }
}

// ---------------------------------------------------------------------------
// K_A: y01 = x @ [W0|W1] via split-bf16 MFMA. BM=128, 4 waves x (32 rows, 64 cols).
// ---------------------------------------------------------------------------
__global__ __launch_bounds__(256) void conv_gemm(
    const float* __restrict__ x, const unsigned short* __restrict__ Wh,
    const unsigned short* __restrict__ Wl,
    float* __restrict__ y0, unsigned short* __restrict__ y1)
{
    __shared__ unsigned short bsh[64 * 64];   // swizzled: granule g at g^(col&7)
    __shared__ unsigned short bsl[64 * 64];
    const int tid = threadIdx.x;
#pragma unroll
    for (int i = 0; i < 2; ++i) {
        const int s = tid + i * 256;
        const int col = s >> 3, o = s & 7;
        const int so = o ^ (col & 7);
        *reinterpret_cast<uint4*>(&bsh[col * 64 + so * 8]) =
            *reinterpret_cast<const uint4*>(&Wh[col * 64 + o * 8]);
        *reinterpret_cast<uint4*>(&bsl[col * 64 + so * 8]) =
            *reinterpret_cast<const uint4*>(&Wl[col * 64 + o * 8]);
    }
    __syncthreads();

    const int w = tid >> 6, lane = tid & 63;
    const int r = lane & 15, kq = lane >> 4;
    const long rowbase = (long)blockIdx.x * 128 + w * 32;

    bf16x8 ah[2][2], al[2][2];
#pragma unroll
    for (int mt = 0; mt < 2; ++mt)
#pragma unroll
        for (int ks = 0; ks < 2; ++ks) {
            const float* xp = x + (rowbase + mt * 16 + r) * FIN + ks * 32 + kq * 8;
            const float4 p0 = *reinterpret_cast<const float4*>(xp);
            const float4 p1 = *reinterpret_cast<const float4*>(xp + 4);
            cvt_split(p0, p1, ah[mt][ks], al[mt][ks]);
        }

    f32x4 acc[2][4];
#pragma unroll
    for (int mt = 0; mt < 2; ++mt)
#pragma unroll
        for (int nt = 0; nt < 4; ++nt) acc[mt][nt] = f32x4{0.f, 0.f, 0.f, 0.f};

#pragma unroll
    for (int nt = 0; nt < 4; ++nt) {
        const int col = nt * 16 + r;
        const int cs = col & 7;
#pragma unroll
        for (int ks = 0; ks < 2; ++ks) {
            const int g = (ks * 4 + kq) ^ cs;
            const bf16x8 bh = *reinterpret_cast<const bf16x8*>(&bsh[col * 64 + g * 8]);
            const bf16x8 bl = *reinterpret_cast<const bf16x8*>(&bsl[col * 64 + g * 8]);
#pragma unroll
            for (int mt = 0; mt < 2; ++mt) {
                acc[mt][nt] = __builtin_amdgcn_mfma_f32_16x16x32_bf16(ah[mt][ks], bh, acc[mt][nt], 0, 0, 0);
                acc[mt][nt] = __builtin_amdgcn_mfma_f32_16x16x32_bf16(ah[mt][ks], bl, acc[mt][nt], 0, 0, 0);
                acc[mt][nt] = __builtin_amdgcn_mfma_f32_16x16x32_bf16(al[mt][ks], bh, acc[mt][nt], 0, 0, 0);
            }
        }
    }

#pragma unroll
    for (int mt = 0; mt < 2; ++mt)
#pragma unroll
        for (int rr = 0; rr < 4; ++rr) {
            const long rg = rowbase + mt * 16 + kq * 4 + rr;
            y0[rg * CH + r]      = acc[mt][0][rr];
            y0[rg * CH + 16 + r] = acc[mt][1][rr];
            y1[rg * CH + r]      = f2bf(acc[mt][2][rr]);
            y1[rg * CH + 16 + r] = f2bf(acc[mt][3][rr]);
        }
}

// ---------------------------------------------------------------------------
// K_B: per-graph CSR build + atomic-free gather + bias + elu.
// One block per graph. Hot loop has ZERO atomics (DS atomic pipe ~214cyc/instr
// was the invariant bottleneck across rounds 2-7).
//   pass1: int-histogram of in-degrees (+ stage y1 to LDS)
//   pass2: wave-0 shfl exclusive prefix scan -> row_start, cursor
//   pass3: fill CSR slots via int fetch-add (slot_src, slot_w)
//   pass4: group of 32 lanes = one dst row (lane = channel); register acc;
//          finalize elu(y0 + bias + acc) -> h (bf16)
// ---------------------------------------------------------------------------
__global__ __launch_bounds__(256) void conv_gather(
    const int* __restrict__ esrc, const int* __restrict__ edst,
    const float* __restrict__ ew, const float* __restrict__ y0,
    const unsigned short* __restrict__ y1, const float* __restrict__ bc,
    unsigned short* __restrict__ h)
{
    __shared__ unsigned short y1s[NPG * CH];     // 16512 B
    __shared__ unsigned short slot_src[EPG];     //  4128 B
    __shared__ float          slot_w[EPG];       //  8256 B
    __shared__ int            row_start[NPG + 2];//  1040 B
    __shared__ int            cursor[NPG];       //  1032 B  (~30.2 KB total)

    const int g   = blockIdx.x;
    const int tid = threadIdx.x;
    const int n0  = g * NPG;
    const long eb = (long)g * EPG;
    const long qb = (long)g * (NPG * CH);

    // zero cursor
    if (tid < NPG) cursor[tid] = 0;
    if (tid + 256 < NPG) cursor[tid + 256] = 0;
    __syncthreads();

    // pass1: histogram in-degrees + stage y1 (16B chunks)
    for (int e = tid; e < EPG; e += 256)
        atomicAdd(&cursor[edst[eb + e] - n0], 1);
#pragma unroll
    for (int i = 0; i < 5; ++i) {
        const int q = tid + i * 256;             // 1032 chunks of 8 ushorts
        if (q < 1032)
            *reinterpret_cast<uint4*>(&y1s[q * 8]) =
                *reinterpret_cast<const uint4*>(&y1[qb + (long)q * 8]);
    }
    __syncthreads();

    // pass2: exclusive prefix scan (wave 0; lane L owns bins [5L, 5L+5))
    if (tid < 64) {
        const int b0 = tid * 5;
        int loc[5], s = 0;
#pragma unroll
        for (int j = 0; j < 5; ++j) {
            const int idx = b0 + j;
            loc[j] = (idx < NPG) ? cursor[idx] : 0;
            s += loc[j];
        }
        int inc = s;
#pragma unroll
        for (int off = 1; off < 64; off <<= 1) {
            const int t = __shfl_up(inc, off, 64);
            if (tid >= off) inc += t;
        }
        int run = inc - s;                       // exclusive
#pragma unroll
        for (int j = 0; j < 5; ++j) {
            const int idx = b0 + j;
            if (idx < NPG) { row_start[idx] = run; cursor[idx] = run; }
            run += loc[j];
        }
        if (tid == 63) row_start[NPG] = inc;     // = EPG
    }
    __syncthreads();

    // pass3: fill CSR slots (int fetch-add; edges re-read, L2-hot)
    for (int e = tid; e < EPG; e += 256) {
        const int dl = edst[eb + e] - n0;
        const int sl = esrc[eb + e] - n0;
        const float w = ew[eb + e];
        const int pos = atomicAdd(&cursor[dl], 1);
        slot_src[pos] = (unsigned short)sl;
        slot_w[pos] = w;
    }
    __syncthreads();

    // pass4: gather. 8 dst rows per pass (group of 32 lanes = one row).
    const int c = tid & 31;
    const int rgrp = tid >> 5;                   // 0..7
#pragma unroll 1
    for (int p = 0; p < 33; ++p) {
        const int n = p * 8 + rgrp;
        if (n >= NPG) break;
        const int pb = row_start[n], pe = row_start[n + 1];
        float acc = 0.f;
        for (int pos = pb; pos < pe; ++pos)
            acc += slot_w[pos] * bf2f(y1s[slot_src[pos] * CH + c]);
        float v = y0[qb + (long)n * CH + c] + bc[c] + acc;
        v = (v > 0.f) ? v : expm1f(v);
        h[qb + (long)n * CH + c] = f2bf(v);
    }
}

// ---------------------------------------------------------------------------
// K2: GEMM1 partials, direct-from-global MFMA. Wave tile 64 rows x 32 cols.
// ---------------------------------------------------------------------------
__global__ __launch_bounds__(256) void gemm1(
    const unsigned short* __restrict__ h, const unsigned short* __restrict__ Wd1T,
    float* __restrict__ part)
{
    const int tid = threadIdx.x, w = tid >> 6, lane = tid & 63;
    const int r = lane & 15, kq = lane >> 4;
    const long m0 = (long)blockIdx.x * 64;
    const int ks = blockIdx.y;
    const int kb0 = ks * 258 / KSPL, kb1 = (ks + 1) * 258 / KSPL;
    const int c0 = w * 32;

    f32x4 acc[4][2];
#pragma unroll
    for (int a = 0; a < 4; ++a)
#pragma unroll
        for (int b = 0; b < 2; ++b) acc[a][b] = f32x4{0.f, 0.f, 0.f, 0.f};

    const unsigned short* ap = h    + (m0 + r) * KTOT + kq * 8;
    const unsigned short* bp = Wd1T + (long)(c0 + r) * KTOT + kq * 8;

    for (int kb = kb0; kb < kb1; ++kb) {
        const int k = kb * 32;
        const bf16x8 b0 = *reinterpret_cast<const bf16x8*>(bp + k);
        const bf16x8 b1 = *reinterpret_cast<const bf16x8*>(bp + 16 * KTOT + k);
#pragma unroll
        for (int mt = 0; mt < 4; ++mt) {
            const bf16x8 a = *reinterpret_cast<const bf16x8*>(ap + mt * 16 * KTOT + k);
            acc[mt][0] = __builtin_amdgcn_mfma_f32_16x16x32_bf16(a, b0, acc[mt][0], 0, 0, 0);
            acc[mt][1] = __builtin_amdgcn_mfma_f32_16x16x32_bf16(a, b1, acc[mt][1], 0, 0, 0);
        }
    }

    float* p = part + ((long)ks * NB + m0) * HID + c0;
#pragma unroll
    for (int mt = 0; mt < 4; ++mt)
#pragma unroll
        for (int rr = 0; rr < 4; ++rr) {
            const int row = mt * 16 + kq * 4 + rr;
            p[(long)row * HID + r]      = acc[mt][0][rr];
            p[(long)row * HID + 16 + r] = acc[mt][1][rr];
        }
}

// ---------------------------------------------------------------------------
// K3: MLP tail. 4 rows/block (1 wave each).
// ---------------------------------------------------------------------------
__global__ __launch_bounds__(256) void mlp_tail(
    const float* __restrict__ part, const float* __restrict__ bd1,
    const float* __restrict__ Wd2, const float* __restrict__ bd2,
    const float* __restrict__ Wd3, const float* __restrict__ bd3,
    const float* __restrict__ Wd4, const float* __restrict__ bd4,
    float* __restrict__ out)
{
    __shared__ float w2[128 * 64];
    __shared__ float w3[64 * 32];
    __shared__ float w4[32];
    __shared__ float h1s[4][128];
    __shared__ float h2s[4][64];
    __shared__ float h3s[4][32];

    const int tid = threadIdx.x;
    for (int i = tid; i < 128 * 64; i += 256) w2[i] = Wd2[i];
    for (int i = tid; i < 64 * 32; i += 256)  w3[i] = Wd3[i];
    if (tid < 32) w4[tid] = Wd4[tid];

    const int r = tid >> 6;
    const int lane = tid & 63;
    const int row = blockIdx.x * 4 + r;

    float s0 = bd1[lane], s1 = bd1[lane + 64];
#pragma unroll 8
    for (int s = 0; s < KSPL; ++s) {
        const float* p = part + ((long)s * NB + row) * HID;
        s0 += p[lane];
        s1 += p[lane + 64];
    }
    h1s[r][lane]      = fmaxf(s0, 0.f);
    h1s[r][lane + 64] = fmaxf(s1, 0.f);
    __syncthreads();

    float s2 = bd2[lane];
#pragma unroll 8
    for (int k = 0; k < 128; ++k) s2 += h1s[r][k] * w2[k * 64 + lane];
    h2s[r][lane] = fmaxf(s2, 0.f);
    __syncthreads();

    if (lane < 32) {
        float s3 = bd3[lane];
#pragma unroll 8
        for (int k = 0; k < 64; ++k) s3 += h2s[r][k] * w3[k * 32 + lane];
        h3s[r][lane] = fmaxf(s3, 0.f);
    }
    __syncthreads();

    float p4 = (lane < 32) ? h3s[r][lane] * w4[lane] : 0.f;
#pragma unroll
    for (int off = 32; off > 0; off >>= 1) p4 += __shfl_down(p4, off, 64);
    if (lane == 0) out[row] = 1.f / (1.f + expf(-(p4 + bd4[0])));
}

// ---------------------------------------------------------------------------
extern "C" void kernel_launch(void* const* d_in, const int* in_sizes, int n_in,
                              void* d_out, int out_size, void* d_ws, size_t ws_size,
                              hipStream_t stream)
{
    const float* x    = (const float*)d_in[0];
    const int*   esrc = (const int*)d_in[1];
    const int*   edst = (const int*)d_in[2];
    const float* ew   = (const float*)d_in[3];
    const float* W0   = (const float*)d_in[4];
    const float* W1   = (const float*)d_in[5];
    const float* bc   = (const float*)d_in[6];
    const float* Wd1  = (const float*)d_in[7];
    const float* bd1  = (const float*)d_in[8];
    const float* Wd2  = (const float*)d_in[9];
    const float* bd2  = (const float*)d_in[10];
    const float* Wd3  = (const float*)d_in[11];
    const float* bd3  = (const float*)d_in[12];
    const float* Wd4  = (const float*)d_in[13];
    const float* bd4  = (const float*)d_in[14];
    float* out = (float*)d_out;

    char* wsb = (char*)d_ws;
    unsigned short* h    = (unsigned short*)wsb;                 // 16,908,288 B
    unsigned short* wd1t = (unsigned short*)(wsb + 16908288);    //  2,113,536 B
    unsigned short* wch  = (unsigned short*)(wsb + 19021824);
    unsigned short* wcl  = (unsigned short*)(wsb + 19030016);
    float*          y0   = (float*)(wsb + 19038208);             // 33,816,576 B
    unsigned short* y1   = (unsigned short*)(wsb + 52854784);    // 16,908,288 B
    float*          part = (float*)(wsb + 19038208);             // reuse y0

    prep_wcat<<<1, 256, 0, stream>>>(W0, W1, wch, wcl);
    wd1_transpose<<<KTOT / 64, 256, 0, stream>>>(Wd1, wd1t);
    conv_gemm<<<NTOT / 128, 256, 0, stream>>>(x, wch, wcl, y0, y1);
    conv_gather<<<NB, 256, 0, stream>>>(esrc, edst, ew, y0, y1, bc, h);
    gemm1<<<dim3(NB / 64, KSPL), 256, 0, stream>>>(h, wd1t, part);
    mlp_tail<<<NB / 4, 256, 0, stream>>>(part, bd1, Wd2, bd2, Wd3, bd3, Wd4, bd4, out);
}

// Round 10
// 196.912 us; speedup vs baseline: 3.1692x; 1.1704x over previous
//
#include <hip/hip_runtime.h>
#include <hip/hip_bf16.h>

#define NPG 258
#define DEG 8
#define EPG 2064          // NPG*DEG
#define CH 32
#define FIN 64
#define NB 1024
#define NTOT (NB * NPG)   // 264192
#define HID 128
#define KTOT 8256         // NPG*CH
#define KSPL 32

typedef __attribute__((ext_vector_type(8))) short bf16x8;
typedef __attribute__((ext_vector_type(4))) float f32x4;

__device__ inline unsigned short f2bf(float f) {
    __hip_bfloat16 b = __float2bfloat16(f);
    return __builtin_bit_cast(unsigned short, b);
}
__device__ inline float bf2f(unsigned short u) {
    return __builtin_bit_cast(float, (unsigned)u << 16);
}
__device__ inline void cvt_split(const float4 a, const float4 b, bf16x8& hi, bf16x8& lo) {
    float f[8] = {a.x, a.y, a.z, a.w, b.x, b.y, b.z, b.w};
#pragma unroll
    for (int j = 0; j < 8; ++j) {
        unsigned short h = f2bf(f[j]);
        hi[j] = (short)h;
        lo[j] = (short)f2bf(f[j] - bf2f(h));
    }
}

// ---------------------------------------------------------------------------
// P: combined prep. Block 0: Wcat hi/lo split.  Blocks 1..129: Wd1 transpose.
// ---------------------------------------------------------------------------
__global__ __launch_bounds__(256) void prep(
    const float* __restrict__ W0, const float* __restrict__ W1,
    unsigned short* __restrict__ Wh, unsigned short* __restrict__ Wl,
    const float* __restrict__ Wd1, unsigned short* __restrict__ Wd1T)
{
    const int tid = threadIdx.x;
    if (blockIdx.x == 0) {
#pragma unroll
        for (int i = 0; i < 16; ++i) {
            const int idx = tid + i * 256;
            const int c = idx >> 6, k = idx & 63;
            const float v = (c < 32) ? W0[k * CH + c] : W1[k * CH + (c - 32)];
            const unsigned short h = f2bf(v);
            Wh[c * 64 + k] = h;
            Wl[c * 64 + k] = f2bf(v - bf2f(h));
        }
        return;
    }
    __shared__ float st[128][65];
    const int k0 = (blockIdx.x - 1) * 64;
#pragma unroll
    for (int i = 0; i < 32; ++i) {
        const int idx = tid + i * 256;
        const int kl = idx >> 7, cc = idx & 127;
        st[cc][kl] = Wd1[(size_t)(k0 + kl) * HID + cc];
    }
    __syncthreads();
    const int cc = tid >> 1, gq = tid & 1;
#pragma unroll
    for (int i = 0; i < 8; ++i) {
        const int ko = (gq + i * 2) * 4;
        ushort4 o;
        o.x = f2bf(st[cc][ko + 0]);
        o.y = f2bf(st[cc][ko + 1]);
        o.z = f2bf(st[cc][ko + 2]);
        o.w = f2bf(st[cc][ko + 3]);
        *reinterpret_cast<ushort4*>(Wd1T + (size_t)cc * KTOT + k0 + ko) = o;
    }
}

// ---------------------------------------------------------------------------
// K1: fully fused ChebConv, one block per graph (512 thr = 8 waves).
//   GEMM phase: y01 = x @ [W0|W1] via split-bf16 MFMA -> y0s(f32)/y1s(bf16) LDS
//   CSR phase : histogram (edges cached in regs) -> scan -> slot fill
//   Gather    : atomic-free per-row gather + bias + elu -> h (bf16 global)
// y0/y1 never touch global memory (round 8 round-tripped 101 MB).
// LDS = 80.4 KB -> 2 blocks/CU (16 waves).
// ---------------------------------------------------------------------------
__global__ __launch_bounds__(512, 4) void conv_fused(
    const float* __restrict__ x, const int* __restrict__ esrc,
    const int* __restrict__ edst, const float* __restrict__ ew,
    const unsigned short* __restrict__ Wh, const unsigned short* __restrict__ Wl,
    const float* __restrict__ bc, unsigned short* __restrict__ h)
{
    __shared__ float          y0s[NPG * CH];      // 33024 B
    __shared__ unsigned short y1s[NPG * CH];      // 16512 B
    __shared__ unsigned short bsh[64 * 64];       //  8192 B (swizzled Wcat hi)
    __shared__ unsigned short bsl[64 * 64];       //  8192 B (swizzled Wcat lo)
    __shared__ unsigned short slot_src[EPG];      //  4128 B
    __shared__ float          slot_w[EPG];        //  8256 B
    __shared__ int            row_start[NPG + 1]; //  1036 B
    __shared__ int            cursor[NPG];        //  1032 B   => 80372 B

    const int g   = blockIdx.x;
    const int tid = threadIdx.x;
    const int n0  = g * NPG;
    const long eb = (long)g * EPG;
    const long qb = (long)g * (NPG * CH);

    // stage swizzled Wcat (one 16B chunk per thread per array) + zero cursor
    {
        const int col = tid >> 3, o = tid & 7;
        const int so = o ^ (col & 7);
        *reinterpret_cast<uint4*>(&bsh[col * 64 + so * 8]) =
            *reinterpret_cast<const uint4*>(&Wh[col * 64 + o * 8]);
        *reinterpret_cast<uint4*>(&bsl[col * 64 + so * 8]) =
            *reinterpret_cast<const uint4*>(&Wl[col * 64 + o * 8]);
    }
    if (tid < NPG) cursor[tid] = 0;
    __syncthreads();

    // ---- phase A: edge load + histogram (edges kept in regs for pass3) ----
    unsigned e_u[4];
    float    e_wv[4];
#pragma unroll
    for (int i = 0; i < 4; ++i) {
        const int e = tid + i * 512;               // 2048 < EPG always valid
        const int sl = esrc[eb + e] - n0;
        const int dl = edst[eb + e] - n0;
        e_u[i] = (unsigned)sl | ((unsigned)dl << 16);
        e_wv[i] = ew[eb + e];
        atomicAdd(&cursor[dl], 1);
    }
    unsigned e_u4 = 0; float e_w4 = 0.f;
    const bool has4 = (tid < EPG - 2048);          // 16 tail edges
    if (has4) {
        const int e = tid + 2048;
        const int sl = esrc[eb + e] - n0;
        const int dl = edst[eb + e] - n0;
        e_u4 = (unsigned)sl | ((unsigned)dl << 16);
        e_w4 = ew[eb + e];
        atomicAdd(&cursor[dl], 1);
    }

    // ---- phase A2: GEMM 258x64 = x @ Wcat (17 row-tiles over 8 waves) ----
    const int w = tid >> 6, lane = tid & 63;
    const int r = lane & 15, kq = lane >> 4;
    for (int t = w; t < 17; t += 8) {
        const int rbase = t * 16;
        const int rowc = min(rbase + r, NPG - 1);  // clamp tail-tile loads
        const float* xp = x + (long)(n0 + rowc) * FIN + kq * 8;
        bf16x8 ah[2], al[2];
#pragma unroll
        for (int ks = 0; ks < 2; ++ks) {
            const float4 p0 = *reinterpret_cast<const float4*>(xp + ks * 32);
            const float4 p1 = *reinterpret_cast<const float4*>(xp + ks * 32 + 4);
            cvt_split(p0, p1, ah[ks], al[ks]);
        }
        f32x4 acc[4];
#pragma unroll
        for (int nt = 0; nt < 4; ++nt) acc[nt] = f32x4{0.f, 0.f, 0.f, 0.f};
#pragma unroll
        for (int nt = 0; nt < 4; ++nt) {
            const int col = nt * 16 + r;
            const int cs = col & 7;
#pragma unroll
            for (int ks = 0; ks < 2; ++ks) {
                const int gg = (ks * 4 + kq) ^ cs;
                const bf16x8 bh = *reinterpret_cast<const bf16x8*>(&bsh[col * 64 + gg * 8]);
                const bf16x8 bl = *reinterpret_cast<const bf16x8*>(&bsl[col * 64 + gg * 8]);
                acc[nt] = __builtin_amdgcn_mfma_f32_16x16x32_bf16(ah[ks], bh, acc[nt], 0, 0, 0);
                acc[nt] = __builtin_amdgcn_mfma_f32_16x16x32_bf16(ah[ks], bl, acc[nt], 0, 0, 0);
                acc[nt] = __builtin_amdgcn_mfma_f32_16x16x32_bf16(al[ks], bh, acc[nt], 0, 0, 0);
            }
        }
        // epilogue -> LDS (C/D: col=lane&15, row=(lane>>4)*4+rr)
#pragma unroll
        for (int rr = 0; rr < 4; ++rr) {
            const int row = rbase + kq * 4 + rr;
            if (row < NPG) {
                y0s[row * CH + r]      = acc[0][rr];
                y0s[row * CH + 16 + r] = acc[1][rr];
                y1s[row * CH + r]      = f2bf(acc[2][rr]);
                y1s[row * CH + 16 + r] = f2bf(acc[3][rr]);
            }
        }
    }
    __syncthreads();

    // ---- pass2: exclusive prefix scan of in-degrees (wave 0) ----
    if (tid < 64) {
        const int b0 = tid * 5;
        int loc[5], s = 0;
#pragma unroll
        for (int j = 0; j < 5; ++j) {
            const int idx = b0 + j;
            loc[j] = (idx < NPG) ? cursor[idx] : 0;
            s += loc[j];
        }
        int inc = s;
#pragma unroll
        for (int off = 1; off < 64; off <<= 1) {
            const int tshf = __shfl_up(inc, off, 64);
            if (tid >= off) inc += tshf;
        }
        int run = inc - s;
#pragma unroll
        for (int j = 0; j < 5; ++j) {
            const int idx = b0 + j;
            if (idx < NPG) { row_start[idx] = run; cursor[idx] = run; }
            run += loc[j];
        }
        if (tid == 63) row_start[NPG] = inc;
    }
    __syncthreads();

    // ---- pass3: CSR slot fill from cached regs (int fetch-add only) ----
#pragma unroll
    for (int i = 0; i < 4; ++i) {
        const int dl = e_u[i] >> 16;
        const int pos = atomicAdd(&cursor[dl], 1);
        slot_src[pos] = (unsigned short)(e_u[i] & 0xFFFFu);
        slot_w[pos] = e_wv[i];
    }
    if (has4) {
        const int dl = e_u4 >> 16;
        const int pos = atomicAdd(&cursor[dl], 1);
        slot_src[pos] = (unsigned short)(e_u4 & 0xFFFFu);
        slot_w[pos] = e_w4;
    }
    __syncthreads();

    // ---- pass4: gather. 32 groups x 16 lanes; lane = 2 channels ----
    const int grp = tid >> 4;                      // 0..31
    const int c = (tid & 15) * 2;
    const float b0 = bc[c], b1 = bc[c + 1];
#pragma unroll 1
    for (int p = 0; p < 9; ++p) {
        const int n = p * 32 + grp;
        if (n >= NPG) break;
        const int pb = row_start[n], pe = row_start[n + 1];
        float a0 = 0.f, a1 = 0.f;
        for (int pos = pb; pos < pe; ++pos) {
            const float wv = slot_w[pos];
            const unsigned u = *reinterpret_cast<const unsigned*>(
                &y1s[slot_src[pos] * CH + c]);
            a0 += wv * bf2f((unsigned short)(u & 0xFFFFu));
            a1 += wv * bf2f((unsigned short)(u >> 16));
        }
        float v0 = y0s[n * CH + c] + b0 + a0;
        float v1 = y0s[n * CH + c + 1] + b1 + a1;
        v0 = (v0 > 0.f) ? v0 : expm1f(v0);
        v1 = (v1 > 0.f) ? v1 : expm1f(v1);
        const unsigned o = (unsigned)f2bf(v0) | ((unsigned)f2bf(v1) << 16);
        *reinterpret_cast<unsigned*>(&h[qb + (long)n * CH + c]) = o;
    }
}

// ---------------------------------------------------------------------------
// K2: GEMM1 partials, direct-from-global MFMA. Wave tile 64 rows x 32 cols.
// ---------------------------------------------------------------------------
__global__ __launch_bounds__(256) void gemm1(
    const unsigned short* __restrict__ h, const unsigned short* __restrict__ Wd1T,
    float* __restrict__ part)
{
    const int tid = threadIdx.x, w = tid >> 6, lane = tid & 63;
    const int r = lane & 15, kq = lane >> 4;
    const long m0 = (long)blockIdx.x * 64;
    const int ks = blockIdx.y;
    const int kb0 = ks * 258 / KSPL, kb1 = (ks + 1) * 258 / KSPL;
    const int c0 = w * 32;

    f32x4 acc[4][2];
#pragma unroll
    for (int a = 0; a < 4; ++a)
#pragma unroll
        for (int b = 0; b < 2; ++b) acc[a][b] = f32x4{0.f, 0.f, 0.f, 0.f};

    const unsigned short* ap = h    + (m0 + r) * KTOT + kq * 8;
    const unsigned short* bp = Wd1T + (long)(c0 + r) * KTOT + kq * 8;

    for (int kb = kb0; kb < kb1; ++kb) {
        const int k = kb * 32;
        const bf16x8 b0 = *reinterpret_cast<const bf16x8*>(bp + k);
        const bf16x8 b1 = *reinterpret_cast<const bf16x8*>(bp + 16 * KTOT + k);
#pragma unroll
        for (int mt = 0; mt < 4; ++mt) {
            const bf16x8 a = *reinterpret_cast<const bf16x8*>(ap + mt * 16 * KTOT + k);
            acc[mt][0] = __builtin_amdgcn_mfma_f32_16x16x32_bf16(a, b0, acc[mt][0], 0, 0, 0);
            acc[mt][1] = __builtin_amdgcn_mfma_f32_16x16x32_bf16(a, b1, acc[mt][1], 0, 0, 0);
        }
    }

    float* p = part + ((long)ks * NB + m0) * HID + c0;
#pragma unroll
    for (int mt = 0; mt < 4; ++mt)
#pragma unroll
        for (int rr = 0; rr < 4; ++rr) {
            const int row = mt * 16 + kq * 4 + rr;
            p[(long)row * HID + r]      = acc[mt][0][rr];
            p[(long)row * HID + 16 + r] = acc[mt][1][rr];
        }
}

// ---------------------------------------------------------------------------
// K3: MLP tail. 4 rows/block (1 wave each).
// ---------------------------------------------------------------------------
__global__ __launch_bounds__(256) void mlp_tail(
    const float* __restrict__ part, const float* __restrict__ bd1,
    const float* __restrict__ Wd2, const float* __restrict__ bd2,
    const float* __restrict__ Wd3, const float* __restrict__ bd3,
    const float* __restrict__ Wd4, const float* __restrict__ bd4,
    float* __restrict__ out)
{
    __shared__ float w2[128 * 64];
    __shared__ float w3[64 * 32];
    __shared__ float w4[32];
    __shared__ float h1s[4][128];
    __shared__ float h2s[4][64];
    __shared__ float h3s[4][32];

    const int tid = threadIdx.x;
    for (int i = tid; i < 128 * 64; i += 256) w2[i] = Wd2[i];
    for (int i = tid; i < 64 * 32; i += 256)  w3[i] = Wd3[i];
    if (tid < 32) w4[tid] = Wd4[tid];

    const int r = tid >> 6;
    const int lane = tid & 63;
    const int row = blockIdx.x * 4 + r;

    float s0 = bd1[lane], s1 = bd1[lane + 64];
#pragma unroll 8
    for (int s = 0; s < KSPL; ++s) {
        const float* p = part + ((long)s * NB + row) * HID;
        s0 += p[lane];
        s1 += p[lane + 64];
    }
    h1s[r][lane]      = fmaxf(s0, 0.f);
    h1s[r][lane + 64] = fmaxf(s1, 0.f);
    __syncthreads();

    float s2 = bd2[lane];
#pragma unroll 8
    for (int k = 0; k < 128; ++k) s2 += h1s[r][k] * w2[k * 64 + lane];
    h2s[r][lane] = fmaxf(s2, 0.f);
    __syncthreads();

    if (lane < 32) {
        float s3 = bd3[lane];
#pragma unroll 8
        for (int k = 0; k < 64; ++k) s3 += h2s[r][k] * w3[k * 32 + lane];
        h3s[r][lane] = fmaxf(s3, 0.f);
    }
    __syncthreads();

    float p4 = (lane < 32) ? h3s[r][lane] * w4[lane] : 0.f;
#pragma unroll
    for (int off = 32; off > 0; off >>= 1) p4 += __shfl_down(p4, off, 64);
    if (lane == 0) out[row] = 1.f / (1.f + expf(-(p4 + bd4[0])));
}

// ---------------------------------------------------------------------------
extern "C" void kernel_launch(void* const* d_in, const int* in_sizes, int n_in,
                              void* d_out, int out_size, void* d_ws, size_t ws_size,
                              hipStream_t stream)
{
    const float* x    = (const float*)d_in[0];
    const int*   esrc = (const int*)d_in[1];
    const int*   edst = (const int*)d_in[2];
    const float* ew   = (const float*)d_in[3];
    const float* W0   = (const float*)d_in[4];
    const float* W1   = (const float*)d_in[5];
    const float* bc   = (const float*)d_in[6];
    const float* Wd1  = (const float*)d_in[7];
    const float* bd1  = (const float*)d_in[8];
    const float* Wd2  = (const float*)d_in[9];
    const float* bd2  = (const float*)d_in[10];
    const float* Wd3  = (const float*)d_in[11];
    const float* bd3  = (const float*)d_in[12];
    const float* Wd4  = (const float*)d_in[13];
    const float* bd4  = (const float*)d_in[14];
    float* out = (float*)d_out;

    // ws: h bf16 @0 (16,908,288) | wd1t bf16 @16908288 (2,113,536)
    //     wch @19021824 (8192) | wcl @19030016 (8192) | part f32 @19038208 (16,777,216)
    char* wsb = (char*)d_ws;
    unsigned short* h    = (unsigned short*)wsb;
    unsigned short* wd1t = (unsigned short*)(wsb + 16908288);
    unsigned short* wch  = (unsigned short*)(wsb + 19021824);
    unsigned short* wcl  = (unsigned short*)(wsb + 19030016);
    float*          part = (float*)(wsb + 19038208);

    prep<<<1 + KTOT / 64, 256, 0, stream>>>(W0, W1, wch, wcl, Wd1, wd1t);
    conv_fused<<<NB, 512, 0, stream>>>(x, esrc, edst, ew, wch, wcl, bc, h);
    gemm1<<<dim3(NB / 64, KSPL), 256, 0, stream>>>(h, wd1t, part);
    mlp_tail<<<NB / 4, 256, 0, stream>>>(part, bd1, Wd2, bd2, Wd3, bd3, Wd4, bd4, out);
}